// Round 3
// baseline (593.989 us; speedup 1.0000x reference)
//
#include <hip/hip_runtime.h>
#include <math.h>

// ArcFaceLoss: B=512, D=512, C=100000, margin=0.5, scale=64
// R3: single fused GEMM. Block tile M=512 (all rows) x N=128 classes, 16 K-chunks.
// W (fp32) read from HBM exactly once; normalization fused (sumsq in regs during
// staging, rsqrt in epilogue). B software-pipelined through registers (prefetch
// chunk i+1 after the publish barrier); A (512KB, L2-resident) via global_load_lds.

#define NB 512
#define ND 512
#define NC 100000
#define BK 32
#define NCHUNK 16            // ND / BK
#define CT 128               // classes per block
#define NT 782               // ceil(NC/CT); padded classes = 100096
#define FSCALE 64.0f
#define C_COS_M 0.8775825618903728f
#define C_SIN_M 0.479425538604203f
#define C_TH  (-0.8775825618903728f)
#define C_MM  0.2397127693021015f

typedef __bf16 bf16x8 __attribute__((ext_vector_type(8)));
typedef __bf16 bf16x4 __attribute__((ext_vector_type(4)));
typedef float  f32x4  __attribute__((ext_vector_type(4)));
typedef __attribute__((address_space(1))) unsigned int GU;
typedef __attribute__((address_space(3))) unsigned int LU;

// xp layout: [chunk i][row b 0..511][32 k], 16B granules XOR-swizzled:
// position = logical_granule ^ ((row>>1)&3)  -> conflict-free ds_read_b128 (R2-verified)

// ---------------- 1) normalize + pack x ----------------
__global__ void pack_x_kernel(const float* __restrict__ x, __bf16* __restrict__ xp) {
  const int b = blockIdx.x;
  const int t = threadIdx.x;                   // 0..127, covers k=4t..4t+3
  float4 v = reinterpret_cast<const float4*>(x + (size_t)b * ND)[t];
  float ss = v.x*v.x + v.y*v.y + v.z*v.z + v.w*v.w;
  #pragma unroll
  for (int m = 1; m < 64; m <<= 1) ss += __shfl_xor(ss, m);
  __shared__ float sred[2];
  if ((t & 63) == 0) sred[t >> 6] = ss;
  __syncthreads();
  const float rn = rsqrtf(fmaxf(sred[0] + sred[1], 1e-24f));
  bf16x4 o;
  o[0] = (__bf16)(v.x * rn); o[1] = (__bf16)(v.y * rn);
  o[2] = (__bf16)(v.z * rn); o[3] = (__bf16)(v.w * rn);
  const int i  = t >> 3;                       // k-chunk
  const int g  = (t >> 1) & 3;                 // logical granule
  const int gp = g ^ ((b >> 1) & 3);           // swizzled position
  __bf16* dst = xp + ((size_t)i * NB + b) * BK + gp * 8 + (t & 1) * 4;
  *reinterpret_cast<bf16x4*>(dst) = o;
}

// ---------------- 2) fp32-accurate target cosine + phi (+ gsum zero) ----------------
__global__ void cosphi_kernel(const float* __restrict__ x, const float* __restrict__ w,
                              const int* __restrict__ tgt,
                              float* __restrict__ cos_t, float* __restrict__ phi_t,
                              float* __restrict__ gsum) {
  const int b = blockIdx.x;
  const int lane = threadIdx.x;                // 0..63
  const int t = tgt[b];
  const float4* xr = reinterpret_cast<const float4*>(x + (size_t)b * ND);
  const float4* wr = reinterpret_cast<const float4*>(w + (size_t)t * ND);
  float dp = 0.f, xs = 0.f, ws = 0.f;
  #pragma unroll
  for (int j = 0; j < 2; ++j) {
    float4 xv = xr[lane * 2 + j];
    float4 wv = wr[lane * 2 + j];
    dp += xv.x*wv.x + xv.y*wv.y + xv.z*wv.z + xv.w*wv.w;
    xs += xv.x*xv.x + xv.y*xv.y + xv.z*xv.z + xv.w*xv.w;
    ws += wv.x*wv.x + wv.y*wv.y + wv.z*wv.z + wv.w*wv.w;
  }
  #pragma unroll
  for (int m = 1; m < 64; m <<= 1) {
    dp += __shfl_xor(dp, m);
    xs += __shfl_xor(xs, m);
    ws += __shfl_xor(ws, m);
  }
  if (lane == 0) {
    float c = dp * rsqrtf(fmaxf(xs, 1e-24f)) * rsqrtf(fmaxf(ws, 1e-24f));
    c = fminf(fmaxf(c, -1.f), 1.f);
    float s = sqrtf(fmaxf(1.f - c * c, 0.f));
    float phi = c * C_COS_M - s * C_SIN_M;
    phi = (c > C_TH) ? phi : (c - C_MM);
    cos_t[b] = c;
    phi_t[b] = phi;
    gsum[b] = 0.f;
  }
}

// ---------------- 3) fused GEMM + partial sum-exp ----------------
// Block: 512 threads (8 waves), 1 block/CU. Wave wv: rows [64wv,64wv+64) x 128 cols,
// 4x8 tiles of mfma_f32_16x16x32_bf16 (acc = 128 VGPRs/lane).
__global__ __launch_bounds__(512, 2) void gemm_lse_kernel(
    const __bf16* __restrict__ xp, const float* __restrict__ w,
    float* __restrict__ gsum) {
  __shared__ __align__(16) __bf16 As[NB * BK];   // 32 KB
  __shared__ __align__(16) __bf16 Bs[CT * BK];   // 8 KB
  __shared__ float wss[CT];

  const int tid  = threadIdx.x;
  const int wv   = tid >> 6;
  const int lane = tid & 63;
  const int nt   = blockIdx.x;

  const int ra = lane & 15;
  const int q  = lane >> 4;
  const int gp = q ^ ((ra >> 1) & 3);

  // B staging role: class-row wr (0..127), 32B part wq (0..3)
  const int wr = tid >> 2;
  const int wq = tid & 3;
  const long long brow = (long long)nt * CT + wr;
  const bool valid = brow < NC;
  const float* wsrc = w + (valid ? brow : 0) * (long long)ND + wq * 8;
  const int bgp = wq ^ ((wr >> 1) & 3);

  const float4 z4 = {0.f, 0.f, 0.f, 0.f};
  float4 p0 = valid ? *reinterpret_cast<const float4*>(wsrc)     : z4;
  float4 p1 = valid ? *reinterpret_cast<const float4*>(wsrc + 4) : z4;

  float wsq = 0.f;
  f32x4 acc[4][8] = {};

  #pragma unroll
  for (int i = 0; i < NCHUNK; ++i) {
    __syncthreads();   // #1: previous compute done -> LDS safe to overwrite
    // --- A stage: 32 KB chunk, async global->LDS, width 16 (L2-resident source) ---
    {
      const char* ga = reinterpret_cast<const char*>(xp)
                       + (size_t)i * (NB * BK * 2) + wv * 4096 + lane * 16;
      char* la = reinterpret_cast<char*>(As) + wv * 4096;
      #pragma unroll
      for (int j = 0; j < 4; ++j)
        __builtin_amdgcn_global_load_lds((const GU*)(ga + j * 1024),
                                         (LU*)(la + j * 1024), 16, 0, 0);
    }
    // --- B stage: cvt prefetched regs -> bf16 LDS; accumulate sumsq ---
    wsq += p0.x*p0.x + p0.y*p0.y + p0.z*p0.z + p0.w*p0.w
         + p1.x*p1.x + p1.y*p1.y + p1.z*p1.z + p1.w*p1.w;
    {
      bf16x8 ob;
      ob[0] = (__bf16)p0.x; ob[1] = (__bf16)p0.y; ob[2] = (__bf16)p0.z; ob[3] = (__bf16)p0.w;
      ob[4] = (__bf16)p1.x; ob[5] = (__bf16)p1.y; ob[6] = (__bf16)p1.z; ob[7] = (__bf16)p1.w;
      *reinterpret_cast<bf16x8*>(Bs + wr * BK + bgp * 8) = ob;
    }
    __syncthreads();   // #2: publish
    // --- prefetch B chunk i+1 into registers (covered by compute below) ---
    if (i < NCHUNK - 1) {
      p0 = valid ? *reinterpret_cast<const float4*>(wsrc + (i + 1) * BK)     : z4;
      p1 = valid ? *reinterpret_cast<const float4*>(wsrc + (i + 1) * BK + 4) : z4;
    }
    // --- compute: 12 ds_read_b128 + 32 MFMA per wave ---
    bf16x8 af[4];
    #pragma unroll
    for (int rt = 0; rt < 4; ++rt)
      af[rt] = *reinterpret_cast<const bf16x8*>(As + (wv * 64 + rt * 16 + ra) * BK + gp * 8);
    #pragma unroll
    for (int ct = 0; ct < 8; ++ct) {
      bf16x8 bfr = *reinterpret_cast<const bf16x8*>(Bs + (ct * 16 + ra) * BK + gp * 8);
      #pragma unroll
      for (int rt = 0; rt < 4; ++rt)
        acc[rt][ct] = __builtin_amdgcn_mfma_f32_16x16x32_bf16(af[rt], bfr, acc[rt][ct], 0, 0, 0);
    }
  }

  // weight sumsq: reduce 4 threads per class row
  wsq += __shfl_xor(wsq, 1);
  wsq += __shfl_xor(wsq, 2);
  if (wq == 0) wss[wr] = wsq;
  __syncthreads();

  // --- epilogue: cos = acc * rsqrt(|w|^2); e = exp(64cos-64); row-sum -> atomic ---
  // C/D 16x16 layout: col = lane&15 (=ra), row = (lane>>4)*4 + reg (=q*4+r)
  float rnw[8];
  #pragma unroll
  for (int ct = 0; ct < 8; ++ct)
    rnw[ct] = rsqrtf(fmaxf(wss[ct * 16 + ra], 1e-24f));
  #pragma unroll
  for (int rt = 0; rt < 4; ++rt) {
    #pragma unroll
    for (int r = 0; r < 4; ++r) {
      float es = 0.f;
      #pragma unroll
      for (int ct = 0; ct < 8; ++ct)
        es += __expf(fmaf(FSCALE, acc[rt][ct][r] * rnw[ct], -FSCALE));
      es += __shfl_xor(es, 1);
      es += __shfl_xor(es, 2);
      es += __shfl_xor(es, 4);
      es += __shfl_xor(es, 8);
      if (ra == 0)
        atomicAdd(&gsum[wv * 64 + rt * 16 + q * 4 + r], es);
    }
  }
}

// ---------------- 4) finalize ----------------
__global__ void finalize_kernel(const float* __restrict__ gsum,
                                const float* __restrict__ cos_t,
                                const float* __restrict__ phi_t,
                                float* __restrict__ out) {
  const int b = threadIdx.x;   // 512
  const float c = cos_t[b];
  const float p = phi_t[b];
  float corr = gsum[b] - __expf(fmaf(FSCALE, c, -FSCALE))
                       + __expf(fmaf(FSCALE, p, -FSCALE));
  corr = fmaxf(corr, 1e-38f);
  float lb = FSCALE + logf(corr) - FSCALE * p;
  #pragma unroll
  for (int m = 1; m < 64; m <<= 1) lb += __shfl_xor(lb, m);
  __shared__ float pr[8];
  if ((b & 63) == 0) pr[b >> 6] = lb;
  __syncthreads();
  if (b == 0) {
    float tot = 0.f;
    #pragma unroll
    for (int j = 0; j < 8; ++j) tot += pr[j];
    out[0] = tot * (1.0f / NB);
  }
}

extern "C" void kernel_launch(void* const* d_in, const int* in_sizes, int n_in,
                              void* d_out, int out_size, void* d_ws, size_t ws_size,
                              hipStream_t stream) {
  const float* x  = (const float*)d_in[0];
  const float* w  = (const float*)d_in[1];
  const int* tgt  = (const int*)d_in[2];
  float* out      = (float*)d_out;

  // workspace: xp (512 KB) | gsum (2 KB) | cos_t (2 KB) | phi_t (2 KB)
  const size_t XP_BYTES = (size_t)NB * ND * 2;
  __bf16* xp   = (__bf16*)d_ws;
  float* gsum  = (float*)((char*)d_ws + XP_BYTES);
  float* cos_t = gsum + NB;
  float* phi_t = cos_t + NB;

  pack_x_kernel<<<NB, 128, 0, stream>>>(x, xp);
  cosphi_kernel<<<NB, 64, 0, stream>>>(x, w, tgt, cos_t, phi_t, gsum);
  gemm_lse_kernel<<<NT, 512, 0, stream>>>(xp, w, gsum);
  finalize_kernel<<<1, 512, 0, stream>>>(gsum, cos_t, phi_t, out);
}